// Round 10
// baseline (116.529 us; speedup 1.0000x reference)
//
#include <hip/hip_runtime.h>

#define BB 2048
#define DD 4096
#define PP 64
#define KK 64
#define EE 8
#define C2 128
#define NBLK BB        // 1 row per block; 4 waves, each owning 16 PATCHES x all 128 channels
#define NGRP 32        // loss-accumulator copies (spread RELAXED adds; R8: ordered RMWs ~30ns ea)

typedef __attribute__((ext_vector_type(8))) short short8;
typedef __attribute__((ext_vector_type(4))) float floatx4;

// Loss accumulators: RELAXED atomicAdds only (R6/R8 lesson: acq-rel agent-scope RMWs serialize
// ~30-70ns each chip-wide -> never per-block). Zero at module load; loss2 resets after reading;
// kernel-boundary ordering publishes adds -> loss2 and reset -> next iteration.
__device__ float g_sum[NGRP][16] = {};

__device__ inline unsigned pack2_trunc(float lo, float hi) { // 2 bf16 (truncate) in 1 u32
    unsigned ul = __builtin_bit_cast(unsigned, lo);
    unsigned uh = __builtin_bit_cast(unsigned, hi);
    return (uh & 0xFFFF0000u) | (ul >> 16);
}

// One row per BLOCK. Patch-split (not channel-split): wave w owns patches [16w,16w+16) and
// ALL 128 channels. Its MFMA A-operand is exactly the 4 float4s it loads DIRECTLY to registers
// -> NO LDS for x at all (R9's gload_lds + vmcnt stage-wait + full-row LDS re-read + 524K
// bank-conflict cycles deleted). The patch-sum is the algorithm's outer reduction, so per-wave
// partials h0/h1 feed the existing cross-wave combine unchanged. Router partials are
// bit-identical to R9 (same 16-patch slice, same fixed merge order). Price: each wave reads
// the full 32KB expert weight (4x redundant, L2-hot, overlapped with MFMA).
__global__ __launch_bounds__(256) void moe_main(
    const float* __restrict__ x, const float* __restrict__ rw,
    const float* __restrict__ ew, const float* __restrict__ eb,
    float* __restrict__ out)
{
    __shared__ float sh_d[4][8];                         // per-wave router partials
    __shared__ float sh_h[4][2];                         // per-wave (h0,h1) patch-partials
    const int lane = threadIdx.x & 63;
    const int w = threadIdx.x >> 6;
    const int b = blockIdx.x;
    const int r = lane & 15, q = lane >> 4;
    const float* xb = x + (size_t)b * DD;

    // ---- own 16 patches, direct to registers in MFMA A-layout:
    // patch p = w*16 + r; k = kb*32 + q*8 + j  (4 float4 loads/lane, issued immediately)
    const float* xbase = xb + (w * 16 + r) * 64;
    float4 v0 = *(const float4*)(xbase + q * 8);
    float4 v1 = *(const float4*)(xbase + q * 8 + 4);
    float4 v2 = *(const float4*)(xbase + 32 + q * 8);
    float4 v3 = *(const float4*)(xbase + 32 + q * 8 + 4);
    float ps[16] = {v0.x, v0.y, v0.z, v0.w, v1.x, v1.y, v1.z, v1.w,
                    v2.x, v2.y, v2.z, v2.w, v3.x, v3.y, v3.z, v3.w};

    // ---- router partial for this wave's 16 patches (identical arithmetic to R9)
    #pragma unroll
    for (int e2 = 0; e2 < 8; ++e2) {
        const float* rwe = rw + e2 * KK;
        float4 a0 = *(const float4*)(rwe + q * 8);
        float4 a1 = *(const float4*)(rwe + q * 8 + 4);
        float4 b0 = *(const float4*)(rwe + 32 + q * 8);
        float4 b1 = *(const float4*)(rwe + 32 + q * 8 + 4);
        float t = ps[0]*a0.x + ps[1]*a0.y + ps[2]*a0.z + ps[3]*a0.w
                + ps[4]*a1.x + ps[5]*a1.y + ps[6]*a1.z + ps[7]*a1.w
                + ps[8]*b0.x + ps[9]*b0.y + ps[10]*b0.z + ps[11]*b0.w
                + ps[12]*b1.x + ps[13]*b1.y + ps[14]*b1.z + ps[15]*b1.w;
        t += __shfl_xor(t, 1);  t += __shfl_xor(t, 2);  t += __shfl_xor(t, 4);
        t += __shfl_xor(t, 8);  t += __shfl_xor(t, 16); t += __shfl_xor(t, 32);
        if (lane == 0) sh_d[w][e2] = t;
    }
    __syncthreads();                                     // all router partials visible

    // ---- merge in FIXED order -> bit-identical d/e/gate across waves
    float d[8];
    #pragma unroll
    for (int e2 = 0; e2 < 8; ++e2)
        d[e2] = ((sh_d[0][e2] + sh_d[1][e2]) + sh_d[2][e2]) + sh_d[3][e2];
    float gate = d[0]; int e = 0;
    #pragma unroll
    for (int e2 = 1; e2 < 8; ++e2)
        if (d[e2] > gate) { gate = d[e2]; e = e2; }

    // ---- select0 + loss adds (RELAXED atomics, spread over 32 copies)
    if (w == 0 && lane < 8) {
        float on = (gate != 0.f) ? 1.f : 0.f;
        out[BB * 2 + b * 8 + lane] = (lane == e) ? on : 0.f;   // select0 (one-hot row)
        atomicAdd(&g_sum[b & (NGRP - 1)][lane], d[lane]);      // sum_b select[b,e]
        if (lane == e) atomicAdd(&g_sum[b & (NGRP - 1)][8 + lane], 1.f);
    }

    // ---- A-frags straight from the registers we already hold (no LDS round-trip)
    uint4 ua, ub;
    ua.x = pack2_trunc(ps[0], ps[1]);  ua.y = pack2_trunc(ps[2],  ps[3]);
    ua.z = pack2_trunc(ps[4], ps[5]);  ua.w = pack2_trunc(ps[6],  ps[7]);
    ub.x = pack2_trunc(ps[8], ps[9]);  ub.y = pack2_trunc(ps[10], ps[11]);
    ub.z = pack2_trunc(ps[12], ps[13]); ub.w = pack2_trunc(ps[14], ps[15]);
    short8 af0 = __builtin_bit_cast(short8, ua);         // kb = 0 (k 0..31)
    short8 af1 = __builtin_bit_cast(short8, ub);         // kb = 1 (k 32..63)

    // ---- expert compute: ALL 8 channel-tiles for own patches; patch-partial accumulation
    const float* we = ew + (size_t)e * (C2 * KK);
    float h0 = 0.f, h1 = 0.f;
    #pragma unroll
    for (int nt = 0; nt < 8; ++nt) {
        float bs = eb[e * C2 + nt * 16 + r];             // c = nt*16 + (lane&15)
        const float* wr = we + (nt * 16 + r) * KK + q * 8;
        float4 w0 = *(const float4*)wr;
        float4 w1 = *(const float4*)(wr + 4);
        float4 w2 = *(const float4*)(wr + 32);
        float4 w3 = *(const float4*)(wr + 36);
        uint4 u0, u1;
        u0.x = pack2_trunc(w0.x, w0.y); u0.y = pack2_trunc(w0.z, w0.w);
        u0.z = pack2_trunc(w1.x, w1.y); u0.w = pack2_trunc(w1.z, w1.w);
        u1.x = pack2_trunc(w2.x, w2.y); u1.y = pack2_trunc(w2.z, w2.w);
        u1.z = pack2_trunc(w3.x, w3.y); u1.w = pack2_trunc(w3.z, w3.w);
        short8 bf0 = __builtin_bit_cast(short8, u0);
        short8 bf1 = __builtin_bit_cast(short8, u1);
        floatx4 a4 = (floatx4){0.f, 0.f, 0.f, 0.f};
        a4 = __builtin_amdgcn_mfma_f32_16x16x32_bf16(af0, bf0, a4, 0, 0, 0);
        a4 = __builtin_amdgcn_mfma_f32_16x16x32_bf16(af1, bf1, a4, 0, 0, 0);
        float hh = 0.f;
        #pragma unroll
        for (int i = 0; i < 4; ++i) {                    // C[row=p=q*4+i][col=c=nt*16+r]
            float z = a4[i] + bs;
            hh = fmaf(z * z, z, hh);
        }
        if (nt < 4) h0 += hh; else h1 += hh;
    }
    #pragma unroll
    for (int off = 1; off < 64; off <<= 1) {
        h0 += __shfl_xor(h0, off);
        h1 += __shfl_xor(h1, off);
    }

    if (lane == 0) { sh_h[w][0] = h0; sh_h[w][1] = h1; }
    __syncthreads();

    if (threadIdx.x == 0) {
        float l0 = gate * (((sh_h[0][0] + sh_h[1][0]) + sh_h[2][0]) + sh_h[3][0]);
        float l1 = gate * (((sh_h[0][1] + sh_h[1][1]) + sh_h[2][1]) + sh_h[3][1]);
        float m = fmaxf(l0, l1);
        float e0 = __expf(l0 - m), e1 = __expf(l1 - m);
        float inv = 1.f / (e0 + e1);
        float2 o; o.x = e0 * inv; o.y = e1 * inv;
        *(float2*)(out + b * 2) = o;
    }
}

// Stage 2 (slim): reduce 32 accumulator copies (512 floats), write loss, reset copies.
__global__ __launch_bounds__(256) void loss2(float* __restrict__ out)
{
    __shared__ float red[16][16];                        // [copy-pair k][slot j]
    __shared__ float m[16];
    const int t = threadIdx.x;
    const int j = t & 15, k = t >> 4;                    // k in 0..15 covers copies k and k+16

    float v = g_sum[k][j] + g_sum[k + 16][j];
    red[k][j] = v;
    __syncthreads();

    // reset for next iteration (reads above are done; kernel boundary publishes to next moe)
    g_sum[k][j] = 0.f;
    g_sum[k + 16][j] = 0.f;

    if (t < 16) {
        float sv = 0.f;
        #pragma unroll
        for (int kk = 0; kk < 16; ++kk) sv += red[kk][t];
        m[t] = sv;
    }
    __syncthreads();
    if (t == 0) {
        float loss = 0.f;
        #pragma unroll
        for (int e2 = 0; e2 < 8; ++e2)
            loss += (m[e2] * (1.f / BB)) * (m[8 + e2] * (1.f / BB));
        out[BB * 2 + BB * 8] = loss * (float)EE;
    }
}

extern "C" void kernel_launch(void* const* d_in, const int* in_sizes, int n_in,
                              void* d_out, int out_size, void* d_ws, size_t ws_size,
                              hipStream_t stream) {
    (void)in_sizes; (void)n_in; (void)out_size; (void)d_ws; (void)ws_size;
    const float* x  = (const float*)d_in[0];
    const float* rw = (const float*)d_in[1];
    const float* ew = (const float*)d_in[2];
    const float* eb = (const float*)d_in[3];
    float* out = (float*)d_out;

    moe_main<<<NBLK, 256, 0, stream>>>(x, rw, ew, eb, out);
    loss2<<<1, 256, 0, stream>>>(out);
}